// Round 10
// baseline (730.574 us; speedup 1.0000x reference)
//
#include <hip/hip_runtime.h>
#include <cmath>

// EMD approxmatch, B=16, N=M=2048, f32. Multi-launch, factorized per-level
// update (nothing [N,M]-shaped). Per level:
//   COL j: A[m] = sum_n e_j*ratioL[n]; rr = satr*min(satr/(satr*A+eps),1);
//          satr = max(satr - rr*A, 0)
//   ROW j: s1 = sum_m e_j*rr; s2 = sum_m e_j*rr*dist; satl=max(satl-rl*s1,0);
//          cost += rl*s2; fused next ratioL via e2 = exp2(c_{j+1}*d2),
//          e_j = e2^4 exactly (levels scale by 4).
// KEY (this round): f32 exp2 underflows to exactly 0 below 2^-149. At early
// levels (|c| up to 9.5e4) almost every pair underflows — wave-uniform skip
// of the exp/sqrt tail when __any(arg > -149) fails (reference computes the
// same exact zeros, so this is value-preserving). Two-tier skip in ROW.
// 8 rows/wave pk-f32 (16 indep chains), satr in LDS, grid=1024 fully resident.

#define NB 16
#define NPTS 2048
#define NH 1024                 // v2f pair count
#define TPB 256
#define EPS_F 1e-9f
#define UFLOW (-149.0f)         // exp2 exact-zero threshold (f32)
#define UFLOW4 (-37.25f)        // e2^4 underflow: 4*arg < -149

typedef float v2f __attribute__((ext_vector_type(2)));

__device__ __forceinline__ float fast_exp2(float x) { return __builtin_amdgcn_exp2f(x); }
__device__ __forceinline__ float fast_sqrt(float x) { return __builtin_amdgcn_sqrtf(x); }
__device__ __forceinline__ v2f v2(float s) { v2f r; r.x = s; r.y = s; return r; }
__device__ __forceinline__ v2f vfma(v2f a, v2f b, v2f c) { return __builtin_elementwise_fma(a, b, c); }
__device__ __forceinline__ v2f vmax0(v2f a) { return __builtin_elementwise_max(a, v2(0.0f)); }
__device__ __forceinline__ v2f vexp2(v2f a) { v2f r; r.x = fast_exp2(a.x); r.y = fast_exp2(a.y); return r; }
__device__ __forceinline__ v2f vsqrt(v2f a) { v2f r; r.x = fast_sqrt(a.x); r.y = fast_sqrt(a.y); return r; }

// 8-way select without runtime indexing (7 cndmask)
__device__ __forceinline__ float sel8(float a0, float a1, float a2, float a3,
                                      float a4, float a5, float a6, float a7, int k) {
    float x = a0;
    x = (k == 1) ? a1 : x; x = (k == 2) ? a2 : x; x = (k == 3) ? a3 : x;
    x = (k == 4) ? a4 : x; x = (k == 5) ? a5 : x; x = (k == 6) ? a6 : x;
    x = (k == 7) ? a7 : x;
    return x;
}
#define SEL8(A, k) sel8(A[0], A[1], A[2], A[3], A[4], A[5], A[6], A[7], k)

// staging: SoA v2f tiles, thread t owns v2f-indices t, t+256, ... (conflict-free)
#define STAGE_C(Cb)                                                        \
    for (int i = tid; i < NH; i += TPB) {                                  \
        const float2* c2 = (const float2*)(Cb) + 3 * i;                    \
        float2 A_ = c2[0], B_ = c2[1], C_ = c2[2];                         \
        Sx[i] = (v2f){A_.x, B_.y};                                         \
        Sy[i] = (v2f){A_.y, C_.x};                                         \
        Sz[i] = (v2f){B_.x, C_.y};                                         \
    }
#define STAGE_W(Wb)                                                        \
    for (int i = tid; i < NH; i += TPB) {                                  \
        float2 w_ = *((const float2*)(Wb) + i);                            \
        Sw[i] = (v2f){w_.x, w_.y};                                         \
    }
#define STAGE_N(Nb)                                                        \
    for (int i = tid; i < NH; i += TPB) {                                  \
        float2 w_ = *((const float2*)(Nb) + i);                            \
        Sn[i] = (v2f){w_.x, w_.y};                                         \
    }

// ratioL[n] = 1/(sum_m exp2(c0*d2) + eps)  (satl = satr = 1). Zeroes costAcc.
__global__ __launch_bounds__(TPB, 4) void row_start(const float* __restrict__ pred,
                                                    const float* __restrict__ gt,
                                                    float* __restrict__ ratioL,
                                                    float* __restrict__ costAcc,
                                                    float c0) {
    __shared__ v2f Sx[NH], Sy[NH], Sz[NH];
    const int b = blockIdx.x >> 6;                    // 64 blocks/batch, 32 rows
    const int base = (blockIdx.x & 63) * 32;
    const int tid = threadIdx.x, wave = tid >> 6, lane = tid & 63;
    if (blockIdx.x == 0 && tid == 0) costAcc[0] = 0.0f;
    const float* Gb = gt + (size_t)b * NPTS * 3;
    STAGE_C(Gb);
    __syncthreads();
    const int own0 = base + wave * 8;
    const float* p0 = pred + ((size_t)b * NPTS + own0) * 3;
    float cx[8], cy[8], cz[8], cb[8];                 // c0 folded into dot form
    v2f a[8];
    #pragma unroll
    for (int r = 0; r < 8; ++r) {
        float px = p0[r * 3], py = p0[r * 3 + 1], pz = p0[r * 3 + 2];
        cx[r] = -2.0f * c0 * px; cy[r] = -2.0f * c0 * py; cz[r] = -2.0f * c0 * pz;
        cb[r] = c0 * (px * px + py * py + pz * pz);
        a[r] = v2(0.0f);
    }
    for (int i = lane; i < NH; i += 64) {
        v2f gx = Sx[i], gy = Sy[i], gz = Sz[i];
        v2f cg2 = vfma(gx, gx, vfma(gy, gy, gz * gz)) * v2(c0);
        #pragma unroll
        for (int r = 0; r < 8; ++r) {
            v2f arg = vfma(v2(cx[r]), gx, vfma(v2(cy[r]), gy,
                      vfma(v2(cz[r]), gz, cg2 + v2(cb[r]))));
            arg = __builtin_elementwise_min(arg, v2(0.0f));
            if (__any(fmaxf(arg.x, arg.y) > UFLOW))
                a[r] += vexp2(arg);
        }
    }
    float as[8];
    #pragma unroll
    for (int r = 0; r < 8; ++r) as[r] = a[r].x + a[r].y;
    #pragma unroll
    for (int o = 1; o < 64; o <<= 1) {
        #pragma unroll
        for (int r = 0; r < 8; ++r) as[r] += __shfl_xor(as[r], o);
    }
    if (lane < 8)
        ratioL[b * NPTS + own0 + lane] = 1.0f / (SEL8(as, lane) + EPS_F);
}

// A[m] = sum_n exp2(c*d2)*ratioL[n]; rr = satr*min(satr/(satr*A+eps),1);
// satr = max(satr - rr*A, 0).  FIRST: satr = 1.
template <bool FIRST>
__global__ __launch_bounds__(TPB, 4) void col_pass(const float* __restrict__ pred,
                                                   const float* __restrict__ gt,
                                                   const float* __restrict__ ratioL,
                                                   float* __restrict__ ratioR,
                                                   float* __restrict__ satr,
                                                   float c) {
    __shared__ v2f Sx[NH], Sy[NH], Sz[NH], Sw[NH];
    const int b = blockIdx.x >> 6;
    const int base = (blockIdx.x & 63) * 32;
    const int tid = threadIdx.x, wave = tid >> 6, lane = tid & 63;
    const float* Pb = pred + (size_t)b * NPTS * 3;
    STAGE_C(Pb);
    STAGE_W(ratioL + b * NPTS);
    __syncthreads();
    const int own0 = base + wave * 8;
    const float* g0 = gt + ((size_t)b * NPTS + own0) * 3;
    float cx[8], cy[8], cz[8], cb[8];
    v2f a[8];
    #pragma unroll
    for (int r = 0; r < 8; ++r) {
        float gx = g0[r * 3], gy = g0[r * 3 + 1], gz = g0[r * 3 + 2];
        cx[r] = -2.0f * c * gx; cy[r] = -2.0f * c * gy; cz[r] = -2.0f * c * gz;
        cb[r] = c * (gx * gx + gy * gy + gz * gz);
        a[r] = v2(0.0f);
    }
    for (int i = lane; i < NH; i += 64) {
        v2f px = Sx[i], py = Sy[i], pz = Sz[i], rl = Sw[i];
        v2f cp2 = vfma(px, px, vfma(py, py, pz * pz)) * v2(c);
        #pragma unroll
        for (int r = 0; r < 8; ++r) {
            v2f arg = vfma(v2(cx[r]), px, vfma(v2(cy[r]), py,
                      vfma(v2(cz[r]), pz, cp2 + v2(cb[r]))));
            arg = __builtin_elementwise_min(arg, v2(0.0f));
            if (__any(fmaxf(arg.x, arg.y) > UFLOW))
                a[r] = vfma(vexp2(arg), rl, a[r]);
        }
    }
    float as[8];
    #pragma unroll
    for (int r = 0; r < 8; ++r) as[r] = a[r].x + a[r].y;
    #pragma unroll
    for (int o = 1; o < 64; o <<= 1) {
        #pragma unroll
        for (int r = 0; r < 8; ++r) as[r] += __shfl_xor(as[r], o);
    }
    if (lane < 8) {
        const int idx = b * NPTS + own0 + lane;
        const float A = SEL8(as, lane);
        const float sr = FIRST ? 1.0f : satr[idx];
        const float ss = fmaf(sr, A, EPS_F);
        const float rr = sr * fminf(sr / ss, 1.0f);
        ratioR[idx] = rr;
        satr[idx] = fmaxf(fmaf(-rr, A, sr), 0.0f);
    }
}

// Last level (exp == 1): A is column-independent = sum_n ratioL[n].
__global__ __launch_bounds__(256) void col_last(const float* __restrict__ ratioL,
                                                float* __restrict__ ratioR,
                                                const float* __restrict__ satr) {
    __shared__ float part[256];
    const int b = blockIdx.x;
    float acc = 0.0f;
    for (int i = threadIdx.x; i < NPTS; i += 256) acc += ratioL[b * NPTS + i];
    part[threadIdx.x] = acc;
    __syncthreads();
    for (int s = 128; s > 0; s >>= 1) {
        if (threadIdx.x < s) part[threadIdx.x] += part[threadIdx.x + s];
        __syncthreads();
    }
    const float sumRL = part[0];
    for (int m = threadIdx.x; m < NPTS; m += 256) {
        const int idx = b * NPTS + m;
        const float sr = satr[idx];
        const float ss = fmaf(sr, sumRL, EPS_F);
        ratioR[idx] = sr * fminf(sr / ss, 1.0f);
    }
}

// MODE 0 (j<=8): e2 = exp2(cq*d2), e1 = (e2^2)^2; an += e2*satr  (cq = c/4)
//   tier-1 skip: all arg2 <= -149  -> e2 == 0 exactly: skip exp/an/s1/s2
//   tier-2 skip: all arg2 <= -37.25 -> e1 == 0 exactly: skip s1/s2/sqrt
// MODE 1 (j==9): e1 = exp2(c*d2); skip when underflowed; an_all = sum satr
// MODE 2 (j==10): e1 = 1; cost only.   FIRST: satl = 1.
template <int MODE, bool FIRST>
__global__ __launch_bounds__(TPB, 4) void row_finish(const float* __restrict__ pred,
                                                     const float* __restrict__ gt,
                                                     float* __restrict__ satl,
                                                     float* __restrict__ ratioL,
                                                     const float* __restrict__ ratioR,
                                                     const float* __restrict__ satr,
                                                     float* __restrict__ costAcc,
                                                     float c1, float cq) {
    __shared__ v2f Sx[NH], Sy[NH], Sz[NH], Sw[NH], Sn[NH];  // 40960 B = 160KiB/4
    const int b = blockIdx.x >> 6;
    const int base = (blockIdx.x & 63) * 32;
    const int tid = threadIdx.x, wave = tid >> 6, lane = tid & 63;
    const float* Gb = gt + (size_t)b * NPTS * 3;
    STAGE_C(Gb);
    STAGE_W(ratioR + b * NPTS);
    if (MODE <= 1) STAGE_N(satr + b * NPTS);
    __syncthreads();
    const int own0 = base + wave * 8;
    const float* p0 = pred + ((size_t)b * NPTS + own0) * 3;
    float nx[8], ny[8], nz[8], p2[8];
    v2f s1[8], s2[8], an[8], anall = v2(0.0f);
    #pragma unroll
    for (int r = 0; r < 8; ++r) {
        float px = p0[r * 3], py = p0[r * 3 + 1], pz = p0[r * 3 + 2];
        nx[r] = -2.0f * px; ny[r] = -2.0f * py; nz[r] = -2.0f * pz;
        p2[r] = px * px + py * py + pz * pz;
        s1[r] = v2(0.0f); s2[r] = v2(0.0f); an[r] = v2(0.0f);
    }
    for (int i = lane; i < NH; i += 64) {
        v2f gx = Sx[i], gy = Sy[i], gz = Sz[i], rr = Sw[i];
        v2f g2 = vfma(gx, gx, vfma(gy, gy, gz * gz));
        v2f nr;
        if (MODE <= 1) nr = Sn[i];
        #pragma unroll
        for (int r = 0; r < 8; ++r) {
            v2f d2 = vmax0(vfma(v2(nx[r]), gx, vfma(v2(ny[r]), gy,
                           vfma(v2(nz[r]), gz, g2 + v2(p2[r])))));
            if (MODE == 0) {
                v2f arg2 = d2 * v2(cq);
                float mx = fmaxf(arg2.x, arg2.y);
                if (__any(mx > UFLOW)) {
                    v2f e2 = vexp2(arg2);
                    an[r] = vfma(e2, nr, an[r]);
                    if (__any(mx > UFLOW4)) {
                        v2f e22 = e2 * e2;
                        v2f t_ = (e22 * e22) * rr;
                        s1[r] += t_;
                        s2[r] = vfma(t_, vsqrt(d2), s2[r]);
                    }
                }
            } else if (MODE == 1) {
                v2f arg = d2 * v2(c1);
                if (__any(fmaxf(arg.x, arg.y) > UFLOW)) {
                    v2f t_ = vexp2(arg) * rr;
                    s1[r] += t_;
                    s2[r] = vfma(t_, vsqrt(d2), s2[r]);
                }
            } else {
                s2[r] = vfma(rr, vsqrt(d2), s2[r]);
            }
        }
        if (MODE == 1) anall += nr;
    }
    float S1[8], S2[8], AN[8], ana = anall.x + anall.y;
    #pragma unroll
    for (int r = 0; r < 8; ++r) {
        S1[r] = s1[r].x + s1[r].y;
        S2[r] = s2[r].x + s2[r].y;
        AN[r] = an[r].x + an[r].y;
    }
    #pragma unroll
    for (int o = 1; o < 64; o <<= 1) {
        #pragma unroll
        for (int r = 0; r < 8; ++r) {
            S2[r] += __shfl_xor(S2[r], o);
            if (MODE <= 1) S1[r] += __shfl_xor(S1[r], o);
            if (MODE == 0) AN[r] += __shfl_xor(AN[r], o);
        }
        if (MODE == 1) ana += __shfl_xor(ana, o);
    }
    float contrib = 0.0f;
    if (lane < 8) {
        const int idx = b * NPTS + own0 + lane;
        const float rl = ratioL[idx];
        contrib = rl * SEL8(S2, lane);
        if (MODE <= 1) {
            const float sl = FIRST ? 1.0f : satl[idx];
            const float nsl = fmaxf(fmaf(-rl, SEL8(S1, lane), sl), 0.0f);
            satl[idx] = nsl;
            const float den = (MODE == 0) ? SEL8(AN, lane) : ana;
            ratioL[idx] = nsl / (den + EPS_F);
        }
    }
    contrib += __shfl_xor(contrib, 1);
    contrib += __shfl_xor(contrib, 2);
    contrib += __shfl_xor(contrib, 4);        // lanes 0..7 hold wave total
    __syncthreads();                           // staging reads done; reuse LDS
    float* scr = (float*)Sx;
    if (lane == 0) scr[wave] = contrib;
    __syncthreads();
    if (tid == 0)
        atomicAdd(costAcc, scr[0] + scr[1] + scr[2] + scr[3]);
}

__global__ void finalize(const float* __restrict__ costAcc, float* __restrict__ out) {
    out[0] = costAcc[0] * (1.0f / (float)NPTS);   // radius = 1
}

extern "C" void kernel_launch(void* const* d_in, const int* in_sizes, int n_in,
                              void* d_out, int out_size, void* d_ws, size_t ws_size,
                              hipStream_t stream) {
    const float* pred = (const float*)d_in[0];
    const float* gt   = (const float*)d_in[1];
    float* out = (float*)d_out;

    float* wsf    = (float*)d_ws;
    float* satl   = wsf;
    float* satr   = wsf + NB * NPTS;
    float* ratioL = wsf + 2 * NB * NPTS;
    float* ratioR = wsf + 3 * NB * NPTS;
    float* costAcc = wsf + 4 * NB * NPTS;

    // c[j] = level_j * log2(e); c[j+1] = c[j]/4 exactly for j<=8
    const double LOG2E = 1.4426950408889634;
    float c[11];
    for (int k = 0; k < 10; ++k) c[k] = (float)(-pow(4.0, (double)(8 - k)) * LOG2E);
    c[10] = 0.0f;

    const int blocks = NB * (NPTS / 32);   // 1024 blocks, 4/CU, fully resident

    row_start<<<blocks, TPB, 0, stream>>>(pred, gt, ratioL, costAcc, c[0]);
    col_pass<true><<<blocks, TPB, 0, stream>>>(pred, gt, ratioL, ratioR, satr, c[0]);
    row_finish<0, true><<<blocks, TPB, 0, stream>>>(pred, gt, satl, ratioL, ratioR, satr,
                                                    costAcc, c[0], c[1]);
    for (int j = 1; j <= 8; ++j) {
        col_pass<false><<<blocks, TPB, 0, stream>>>(pred, gt, ratioL, ratioR, satr, c[j]);
        row_finish<0, false><<<blocks, TPB, 0, stream>>>(pred, gt, satl, ratioL, ratioR,
                                                         satr, costAcc, c[j], c[j + 1]);
    }
    col_pass<false><<<blocks, TPB, 0, stream>>>(pred, gt, ratioL, ratioR, satr, c[9]);
    row_finish<1, false><<<blocks, TPB, 0, stream>>>(pred, gt, satl, ratioL, ratioR, satr,
                                                     costAcc, c[9], 0.0f);
    col_last<<<NB, 256, 0, stream>>>(ratioL, ratioR, satr);
    row_finish<2, false><<<blocks, TPB, 0, stream>>>(pred, gt, satl, ratioL, ratioR, satr,
                                                     costAcc, 0.0f, 0.0f);
    finalize<<<1, 1, 0, stream>>>(costAcc, out);
}

// Round 11
// 618.248 us; speedup vs baseline: 1.1817x; 1.1817x over previous
//
#include <hip/hip_runtime.h>
#include <cmath>

// EMD approxmatch, B=16, N=M=2048, f32. Multi-launch (kernel boundary = sync),
// factorized per-level update (nothing [N,M]-shaped):
//   COL j: A[m] = sum_n e_j*ratioL[n]; rr = satr*min(satr/(satr*A+eps),1);
//          satr = max(satr - rr*A, 0)
//   ROW j: s1 = sum_m e_j*rr; s2 = sum_m e_j*rr*dist; satl=max(satl-rl*s1,0);
//          cost += rl*s2; fused next ratioL via e2 = exp2(c_{j+1}*d2),
//          e_j = e2^4 exactly (levels scale by 4).
// Underflow skip (early levels only): f32 exp2 is EXACTLY 0 below 2^-149, so
// a granule (64 lanes x 2 packed x 4 rows) whose args all underflow
// contributes exact zeros — one __any-vote branch per ITERATION around the
// whole tail (round 10's per-r branches caused spills; this keeps the
// round-9 body intact and adds a single branch). SKIP instantiated only for
// ROW j<=2 / COL j<=3 / row_start where the skip probability is high.

#define NB 16
#define NPTS 2048
#define NH 1024                 // v2f pair count
#define TPB 256
#define EPS_F 1e-9f
#define UFLOW (-149.0f)         // exp2 exact-zero threshold (f32)

typedef float v2f __attribute__((ext_vector_type(2)));

__device__ __forceinline__ float fast_exp2(float x) { return __builtin_amdgcn_exp2f(x); }
__device__ __forceinline__ float fast_sqrt(float x) { return __builtin_amdgcn_sqrtf(x); }
__device__ __forceinline__ v2f v2(float s) { v2f r; r.x = s; r.y = s; return r; }
__device__ __forceinline__ v2f vfma(v2f a, v2f b, v2f c) { return __builtin_elementwise_fma(a, b, c); }
__device__ __forceinline__ v2f vmax0(v2f a) { return __builtin_elementwise_max(a, v2(0.0f)); }
__device__ __forceinline__ v2f vmin2(v2f a, v2f b) { return __builtin_elementwise_min(a, b); }
__device__ __forceinline__ v2f vmax2(v2f a, v2f b) { return __builtin_elementwise_max(a, b); }
__device__ __forceinline__ v2f vexp2(v2f a) { v2f r; r.x = fast_exp2(a.x); r.y = fast_exp2(a.y); return r; }
__device__ __forceinline__ v2f vsqrt(v2f a) { v2f r; r.x = fast_sqrt(a.x); r.y = fast_sqrt(a.y); return r; }

// 4-way select without runtime indexing (3 cndmask)
__device__ __forceinline__ float sel4(float a0, float a1, float a2, float a3, int k) {
    float x = a0;
    x = (k == 1) ? a1 : x; x = (k == 2) ? a2 : x; x = (k == 3) ? a3 : x;
    return x;
}
#define SEL4(A, k) sel4(A[0], A[1], A[2], A[3], k)

// staging: SoA v2f tiles, thread t owns v2f-indices t, t+256, ... (conflict-free)
#define STAGE_CW(Cb, Wb)                                                   \
    for (int i = tid; i < NH; i += TPB) {                                  \
        const float2* c2 = (const float2*)(Cb) + 3 * i;                    \
        float2 A_ = c2[0], B_ = c2[1], C_ = c2[2];                         \
        Sx[i] = (v2f){A_.x, B_.y};                                         \
        Sy[i] = (v2f){A_.y, C_.x};                                         \
        Sz[i] = (v2f){B_.x, C_.y};                                         \
        float2 w_ = *((const float2*)(Wb) + i);                            \
        Sw[i] = (v2f){w_.x, w_.y};                                         \
    }
#define STAGE_C(Cb)                                                        \
    for (int i = tid; i < NH; i += TPB) {                                  \
        const float2* c2 = (const float2*)(Cb) + 3 * i;                    \
        float2 A_ = c2[0], B_ = c2[1], C_ = c2[2];                         \
        Sx[i] = (v2f){A_.x, B_.y};                                         \
        Sy[i] = (v2f){A_.y, C_.x};                                         \
        Sz[i] = (v2f){B_.x, C_.y};                                         \
    }

// ratioL[n] = 1/(sum_m exp2(c0*d2) + eps)  (satl = satr = 1). Zeroes costAcc.
// Level 0 always SKIP-qualified (|c0| huge): one vote per iteration.
__global__ __launch_bounds__(TPB, 5) void row_start(const float* __restrict__ pred,
                                                    const float* __restrict__ gt,
                                                    float* __restrict__ ratioL,
                                                    float* __restrict__ costAcc,
                                                    float c0) {
    __shared__ v2f Sx[NH], Sy[NH], Sz[NH];
    const int b = blockIdx.x >> 7;                    // 128 blocks/batch, 16 rows
    const int base = (blockIdx.x & 127) * 16;
    const int tid = threadIdx.x, wave = tid >> 6, lane = tid & 63;
    if (blockIdx.x == 0 && tid == 0) costAcc[0] = 0.0f;
    const float* Gb = gt + (size_t)b * NPTS * 3;
    STAGE_C(Gb);
    __syncthreads();
    const int own0 = base + wave * 4;
    const float* p0 = pred + ((size_t)b * NPTS + own0) * 3;
    float cx[4], cy[4], cz[4], cb[4];                 // c0 folded into dot form
    v2f a[4];
    #pragma unroll
    for (int r = 0; r < 4; ++r) {
        float px = p0[r * 3], py = p0[r * 3 + 1], pz = p0[r * 3 + 2];
        cx[r] = -2.0f * c0 * px; cy[r] = -2.0f * c0 * py; cz[r] = -2.0f * c0 * pz;
        cb[r] = c0 * (px * px + py * py + pz * pz);
        a[r] = v2(0.0f);
    }
    for (int i = lane; i < NH; i += 64) {
        v2f gx = Sx[i], gy = Sy[i], gz = Sz[i];
        v2f cg2 = vfma(gx, gx, vfma(gy, gy, gz * gz)) * v2(c0);
        v2f arg[4];
        #pragma unroll
        for (int r = 0; r < 4; ++r)
            arg[r] = vmin2(vfma(v2(cx[r]), gx, vfma(v2(cy[r]), gy,
                           vfma(v2(cz[r]), gz, cg2 + v2(cb[r])))), v2(0.0f));
        v2f m2 = vmax2(vmax2(arg[0], arg[1]), vmax2(arg[2], arg[3]));
        if (__any(fmaxf(m2.x, m2.y) > UFLOW)) {
            #pragma unroll
            for (int r = 0; r < 4; ++r) a[r] += vexp2(arg[r]);
        }
    }
    float as[4];
    #pragma unroll
    for (int r = 0; r < 4; ++r) as[r] = a[r].x + a[r].y;
    #pragma unroll
    for (int o = 1; o < 64; o <<= 1) {
        #pragma unroll
        for (int r = 0; r < 4; ++r) as[r] += __shfl_xor(as[r], o);
    }
    if (lane < 4)
        ratioL[b * NPTS + own0 + lane] = 1.0f / (SEL4(as, lane) + EPS_F);
}

// A[m] = sum_n exp2(c*d2)*ratioL[n]; rr = satr*min(satr/(satr*A+eps),1);
// satr = max(satr - rr*A, 0).  FIRST: satr = 1.  SKIP: vote per iteration.
template <bool FIRST, bool SKIP>
__global__ __launch_bounds__(TPB, 5) void col_pass(const float* __restrict__ pred,
                                                   const float* __restrict__ gt,
                                                   const float* __restrict__ ratioL,
                                                   float* __restrict__ ratioR,
                                                   float* __restrict__ satr,
                                                   float c) {
    __shared__ v2f Sx[NH], Sy[NH], Sz[NH], Sw[NH];
    const int b = blockIdx.x >> 7;
    const int base = (blockIdx.x & 127) * 16;
    const int tid = threadIdx.x, wave = tid >> 6, lane = tid & 63;
    const float* Pb = pred + (size_t)b * NPTS * 3;
    STAGE_CW(Pb, ratioL + b * NPTS);
    __syncthreads();
    const int own0 = base + wave * 4;
    const float* g0 = gt + ((size_t)b * NPTS + own0) * 3;
    float cx[4], cy[4], cz[4], cb[4];
    v2f a[4];
    #pragma unroll
    for (int r = 0; r < 4; ++r) {
        float gx = g0[r * 3], gy = g0[r * 3 + 1], gz = g0[r * 3 + 2];
        cx[r] = -2.0f * c * gx; cy[r] = -2.0f * c * gy; cz[r] = -2.0f * c * gz;
        cb[r] = c * (gx * gx + gy * gy + gz * gz);
        a[r] = v2(0.0f);
    }
    for (int i = lane; i < NH; i += 64) {
        v2f px = Sx[i], py = Sy[i], pz = Sz[i];
        v2f cp2 = vfma(px, px, vfma(py, py, pz * pz)) * v2(c);
        v2f arg[4];
        #pragma unroll
        for (int r = 0; r < 4; ++r)
            arg[r] = vmin2(vfma(v2(cx[r]), px, vfma(v2(cy[r]), py,
                           vfma(v2(cz[r]), pz, cp2 + v2(cb[r])))), v2(0.0f));
        bool take = true;
        if (SKIP) {
            v2f m2 = vmax2(vmax2(arg[0], arg[1]), vmax2(arg[2], arg[3]));
            take = __any(fmaxf(m2.x, m2.y) > UFLOW);
        }
        if (take) {
            v2f rl = Sw[i];
            #pragma unroll
            for (int r = 0; r < 4; ++r) a[r] = vfma(vexp2(arg[r]), rl, a[r]);
        }
    }
    float as[4];
    #pragma unroll
    for (int r = 0; r < 4; ++r) as[r] = a[r].x + a[r].y;
    #pragma unroll
    for (int o = 1; o < 64; o <<= 1) {
        #pragma unroll
        for (int r = 0; r < 4; ++r) as[r] += __shfl_xor(as[r], o);
    }
    if (lane < 4) {
        const int idx = b * NPTS + own0 + lane;
        const float A = SEL4(as, lane);
        const float sr = FIRST ? 1.0f : satr[idx];
        const float ss = fmaf(sr, A, EPS_F);
        const float rr = sr * fminf(sr / ss, 1.0f);
        ratioR[idx] = rr;
        satr[idx] = fmaxf(fmaf(-rr, A, sr), 0.0f);
    }
}

// Last level (exp == 1): A is column-independent = sum_n ratioL[n].
__global__ __launch_bounds__(256) void col_last(const float* __restrict__ ratioL,
                                                float* __restrict__ ratioR,
                                                const float* __restrict__ satr) {
    __shared__ float part[256];
    const int b = blockIdx.x;
    float acc = 0.0f;
    for (int i = threadIdx.x; i < NPTS; i += 256) acc += ratioL[b * NPTS + i];
    part[threadIdx.x] = acc;
    __syncthreads();
    for (int s = 128; s > 0; s >>= 1) {
        if (threadIdx.x < s) part[threadIdx.x] += part[threadIdx.x + s];
        __syncthreads();
    }
    const float sumRL = part[0];
    for (int m = threadIdx.x; m < NPTS; m += 256) {
        const int idx = b * NPTS + m;
        const float sr = satr[idx];
        const float ss = fmaf(sr, sumRL, EPS_F);
        ratioR[idx] = sr * fminf(sr / ss, 1.0f);
    }
}

// MODE 0 (j<=8): e2 = exp2(cq*d2), e1 = (e2^2)^2; an += e2*satr  (cq = c/4)
//   SKIP: survive iff any d2 < thr (= -149/cq); one vote per iteration.
// MODE 1 (j==9): e1 = exp2(c*d2); an_all = sum satr
// MODE 2 (j==10): e1 = 1; cost only.   FIRST: satl = 1.
template <int MODE, bool FIRST, bool SKIP>
__global__ __launch_bounds__(TPB, 5) void row_finish(const float* __restrict__ pred,
                                                     const float* __restrict__ gt,
                                                     float* __restrict__ satl,
                                                     float* __restrict__ ratioL,
                                                     const float* __restrict__ ratioR,
                                                     const float* __restrict__ satr,
                                                     float* __restrict__ costAcc,
                                                     float c1, float cq) {
    __shared__ v2f Sx[NH], Sy[NH], Sz[NH], Sw[NH];   // 32768 B
    const int b = blockIdx.x >> 7;
    const int base = (blockIdx.x & 127) * 16;
    const int tid = threadIdx.x, wave = tid >> 6, lane = tid & 63;
    const float* Gb = gt + (size_t)b * NPTS * 3;
    STAGE_CW(Gb, ratioR + b * NPTS);
    __syncthreads();
    const int own0 = base + wave * 4;
    const float* p0 = pred + ((size_t)b * NPTS + own0) * 3;
    const float2* nrp = (const float2*)(satr + b * NPTS);   // L1/L2-hot
    const float thr = (MODE == 0) ? (UFLOW / cq) : 0.0f;    // cq<0 -> thr>0
    float nx[4], ny[4], nz[4], p2[4];
    v2f s1[4], s2[4], an[4], anall = v2(0.0f);
    #pragma unroll
    for (int r = 0; r < 4; ++r) {
        float px = p0[r * 3], py = p0[r * 3 + 1], pz = p0[r * 3 + 2];
        nx[r] = -2.0f * px; ny[r] = -2.0f * py; nz[r] = -2.0f * pz;
        p2[r] = px * px + py * py + pz * pz;
        s1[r] = v2(0.0f); s2[r] = v2(0.0f); an[r] = v2(0.0f);
    }
    for (int i = lane; i < NH; i += 64) {
        v2f gx = Sx[i], gy = Sy[i], gz = Sz[i];
        v2f g2 = vfma(gx, gx, vfma(gy, gy, gz * gz));
        v2f d2a[4];
        #pragma unroll
        for (int r = 0; r < 4; ++r)
            d2a[r] = vmax0(vfma(v2(nx[r]), gx, vfma(v2(ny[r]), gy,
                           vfma(v2(nz[r]), gz, g2 + v2(p2[r])))));
        if (MODE == 0) {
            bool take = true;
            if (SKIP) {
                v2f mn = vmin2(vmin2(d2a[0], d2a[1]), vmin2(d2a[2], d2a[3]));
                take = __any(fminf(mn.x, mn.y) < thr);
            }
            if (take) {
                v2f rr = Sw[i];
                float2 q = nrp[i];
                v2f nr = (v2f){q.x, q.y};
                #pragma unroll
                for (int r = 0; r < 4; ++r) {
                    v2f e2 = vexp2(d2a[r] * v2(cq));
                    v2f e22 = e2 * e2;
                    an[r] = vfma(e2, nr, an[r]);
                    v2f t_ = (e22 * e22) * rr;
                    s1[r] += t_;
                    s2[r] = vfma(t_, vsqrt(d2a[r]), s2[r]);
                }
            }
        } else if (MODE == 1) {
            v2f rr = Sw[i];
            float2 q = nrp[i];
            anall += (v2f){q.x, q.y};
            #pragma unroll
            for (int r = 0; r < 4; ++r) {
                v2f t_ = vexp2(d2a[r] * v2(c1)) * rr;
                s1[r] += t_;
                s2[r] = vfma(t_, vsqrt(d2a[r]), s2[r]);
            }
        } else {
            v2f rr = Sw[i];
            #pragma unroll
            for (int r = 0; r < 4; ++r)
                s2[r] = vfma(rr, vsqrt(d2a[r]), s2[r]);
        }
    }
    float S1[4], S2[4], AN[4], ana = anall.x + anall.y;
    #pragma unroll
    for (int r = 0; r < 4; ++r) {
        S1[r] = s1[r].x + s1[r].y;
        S2[r] = s2[r].x + s2[r].y;
        AN[r] = an[r].x + an[r].y;
    }
    #pragma unroll
    for (int o = 1; o < 64; o <<= 1) {
        #pragma unroll
        for (int r = 0; r < 4; ++r) {
            S2[r] += __shfl_xor(S2[r], o);
            if (MODE <= 1) S1[r] += __shfl_xor(S1[r], o);
            if (MODE == 0) AN[r] += __shfl_xor(AN[r], o);
        }
        if (MODE == 1) ana += __shfl_xor(ana, o);
    }
    float contrib = 0.0f;
    if (lane < 4) {
        const int idx = b * NPTS + own0 + lane;
        const float rl = ratioL[idx];
        contrib = rl * SEL4(S2, lane);
        if (MODE <= 1) {
            const float sl = FIRST ? 1.0f : satl[idx];
            const float nsl = fmaxf(fmaf(-rl, SEL4(S1, lane), sl), 0.0f);
            satl[idx] = nsl;
            const float den = (MODE == 0) ? SEL4(AN, lane) : ana;
            ratioL[idx] = nsl / (den + EPS_F);
        }
    }
    contrib += __shfl_xor(contrib, 1);
    contrib += __shfl_xor(contrib, 2);       // lanes 0..3 hold wave total
    __syncthreads();                          // staging reads done; reuse LDS
    float* scr = (float*)Sx;
    if (lane == 0) scr[wave] = contrib;
    __syncthreads();
    if (tid == 0)
        atomicAdd(costAcc, scr[0] + scr[1] + scr[2] + scr[3]);
}

__global__ void finalize(const float* __restrict__ costAcc, float* __restrict__ out) {
    out[0] = costAcc[0] * (1.0f / (float)NPTS);   // radius = 1
}

extern "C" void kernel_launch(void* const* d_in, const int* in_sizes, int n_in,
                              void* d_out, int out_size, void* d_ws, size_t ws_size,
                              hipStream_t stream) {
    const float* pred = (const float*)d_in[0];
    const float* gt   = (const float*)d_in[1];
    float* out = (float*)d_out;

    float* wsf    = (float*)d_ws;
    float* satl   = wsf;
    float* satr   = wsf + NB * NPTS;
    float* ratioL = wsf + 2 * NB * NPTS;
    float* ratioR = wsf + 3 * NB * NPTS;
    float* costAcc = wsf + 4 * NB * NPTS;

    // c[j] = level_j * log2(e); c[j+1] = c[j]/4 exactly for j<=8
    const double LOG2E = 1.4426950408889634;
    float c[11];
    for (int k = 0; k < 10; ++k) c[k] = (float)(-pow(4.0, (double)(8 - k)) * LOG2E);
    c[10] = 0.0f;

    const int blocks = NB * (NPTS / 16);   // 2048 blocks, 5 resident/CU

    row_start<<<blocks, TPB, 0, stream>>>(pred, gt, ratioL, costAcc, c[0]);
    // j = 0
    col_pass<true, true><<<blocks, TPB, 0, stream>>>(pred, gt, ratioL, ratioR, satr, c[0]);
    row_finish<0, true, true><<<blocks, TPB, 0, stream>>>(pred, gt, satl, ratioL, ratioR,
                                                          satr, costAcc, c[0], c[1]);
    // j = 1..2: both phases skip-qualified
    for (int j = 1; j <= 2; ++j) {
        col_pass<false, true><<<blocks, TPB, 0, stream>>>(pred, gt, ratioL, ratioR, satr, c[j]);
        row_finish<0, false, true><<<blocks, TPB, 0, stream>>>(pred, gt, satl, ratioL, ratioR,
                                                               satr, costAcc, c[j], c[j + 1]);
    }
    // j = 3: col still skips often; row doesn't
    col_pass<false, true><<<blocks, TPB, 0, stream>>>(pred, gt, ratioL, ratioR, satr, c[3]);
    row_finish<0, false, false><<<blocks, TPB, 0, stream>>>(pred, gt, satl, ratioL, ratioR,
                                                            satr, costAcc, c[3], c[4]);
    // j = 4..8: dense
    for (int j = 4; j <= 8; ++j) {
        col_pass<false, false><<<blocks, TPB, 0, stream>>>(pred, gt, ratioL, ratioR, satr, c[j]);
        row_finish<0, false, false><<<blocks, TPB, 0, stream>>>(pred, gt, satl, ratioL, ratioR,
                                                                satr, costAcc, c[j], c[j + 1]);
    }
    col_pass<false, false><<<blocks, TPB, 0, stream>>>(pred, gt, ratioL, ratioR, satr, c[9]);
    row_finish<1, false, false><<<blocks, TPB, 0, stream>>>(pred, gt, satl, ratioL, ratioR,
                                                            satr, costAcc, c[9], 0.0f);
    col_last<<<NB, 256, 0, stream>>>(ratioL, ratioR, satr);
    row_finish<2, false, false><<<blocks, TPB, 0, stream>>>(pred, gt, satl, ratioL, ratioR,
                                                            satr, costAcc, 0.0f, 0.0f);
    finalize<<<1, 1, 0, stream>>>(costAcc, out);
}